// Round 13
// baseline (78.379 us; speedup 1.0000x reference)
//
#include <hip/hip_runtime.h>

// Top1Gate via bf16x3-split MFMA GEMM, v14-DIAG (= v6 with K-sweep x3).
// DIAGNOSTIC ROUND: the gate has never appeared in rocprof top-5 (fill
// kernels at ~75us dominate). Repeat the whole K-sweep REP=3 times (acc
// re-zeroed per rep -> identical output) to push gate dur past the fills
// and expose FETCH_SIZE / VALUBusy / MfmaUtil / Occupancy / bank conflicts.
// Also discriminates: warm reps fast => DRAM-side limit; equal => CU-path.
// Math/schedule per rep is byte-identical to v6 (37.1 us best).

typedef float  f32x4  __attribute__((ext_vector_type(4)));
typedef short  bf16x8 __attribute__((ext_vector_type(8)));

constexpr int BATCH = 16384;
constexpr int DM    = 2048;
constexpr int NE    = 64;
constexpr int BM    = 32;          // rows per block
constexpr int NT    = 256;         // 4 waves = 4 k-quarters
constexpr int REP   = 3;           // diagnostic sweep repeat

// wf layout (d_ws, ushort): [ks=64][term=2][tile=4][lane=64][j=8]
// value = w_term[expert = tile*16 + (lane&15)][k = ks*32 + (lane>>4)*8 + j]

__device__ __forceinline__ void split_bf16(float f, unsigned short& hi, unsigned short& lo) {
    unsigned u  = __float_as_uint(f);
    unsigned h  = (u + 0x8000u) >> 16;           // round-half-up to bf16
    float    hf = __uint_as_float(h << 16);
    unsigned l  = __float_as_uint(f - hf) >> 16; // truncate residual
    hi = (unsigned short)h;
    lo = (unsigned short)l;
}

__global__ __launch_bounds__(256, 1)
void wconv_kernel(const float* __restrict__ w, unsigned short* __restrict__ wf) {
    int i  = blockIdx.x * 256 + threadIdx.x;     // 0..131071
    int ks = i >> 11;
    int n  = (i >> 9) & 3;
    int l  = (i >> 3) & 63;
    int j  = i & 7;
    int e  = n * 16 + (l & 15);
    int k  = ks * 32 + (l >> 4) * 8 + j;
    float v = w[(size_t)e * DM + k];
    unsigned short hi, lo;
    split_bf16(v, hi, lo);
    int base = ((ks * 2 + 0) * 4 + n) * 512 + l * 8 + j;
    wf[base]        = hi;               // term 0
    wf[base + 2048] = lo;               // term 1
}

struct BSet { bf16x8 v[8]; };   // [term=2(hi,lo)][tile=4] for one 32-k step

__global__ __launch_bounds__(NT, 2)
void gate_kernel(const float* __restrict__ x,
                 const unsigned short* __restrict__ wf,
                 float* __restrict__ out) {
    __shared__ alignas(16) float xs[4][16 * 32 * 4];   // 4-slot ring x 8 KB
    __shared__ float lg[BM][NE + 1];                   // stride 65
    __shared__ int   s_idx[BM];

    const int t     = threadIdx.x;
    const int lane  = t & 63;
    const int q     = t >> 6;                 // k-quarter 0..3
    const int row0  = blockIdx.x * BM;
    const int phase = (blockIdx.x & 15) << 1; // EVEN de-phase: preserves kblk pairing

    f32x4 acc[2][4];

    auto kbOf = [&](int c) { return ((c + phase) >> 1) & 15; };

    auto stage_x = [&](int c, int b) {
        const int h = c & 1;
        const float* xg = x + (size_t)(row0 + h * 16) * DM + kbOf(c) * 128;
        #pragma unroll
        for (int i = 0; i < 2; ++i) {
            int d    = i * NT + t;            // 0..511 linear dest f4 slot
            int r    = d >> 5;                // row 0..15
            int sdst = d & 31;
            int ssrc = sdst ^ ((r & 7) << 2); // pre-swizzled source (linear LDS dest)
            __builtin_amdgcn_global_load_lds(
                (const __attribute__((address_space(1))) void*)(xg + (size_t)r * DM + ssrc * 4),
                (__attribute__((address_space(3))) void*)(&xs[b][d * 4]),
                16, 0, 0);
        }
    };

    auto load_b = [&](int c, BSet& B) {
        int ks = kbOf(c) * 4 + q;
        const unsigned short* wg = wf + (size_t)ks * 4096 + lane * 8;
        #pragma unroll
        for (int f = 0; f < 8; ++f)           // f = term*4 + tile
            B.v[f] = *(const bf16x8*)(wg + (size_t)f * 512);
    };

    auto compute = [&](int b, int hh, const BSet& B) {
        const int rA = lane & 15;
        const int s0 = q * 8 + ((lane >> 4) << 1);
        const int xr = (rA & 7) << 2;
        f32x4 a0 = *(const f32x4*)&xs[b][(rA * 32 + ((s0 + 0) ^ xr)) * 4];
        f32x4 a1 = *(const f32x4*)&xs[b][(rA * 32 + ((s0 + 1) ^ xr)) * 4];
        bf16x8 ahi, alo;
        #pragma unroll
        for (int j = 0; j < 8; ++j) {
            float f = (j < 4) ? a0[j] : a1[j - 4];
            unsigned short h, l;
            split_bf16(f, h, l);
            ahi[j] = (short)h;
            alo[j] = (short)l;
        }
        #pragma unroll
        for (int n = 0; n < 4; ++n) {
            acc[hh][n] = __builtin_amdgcn_mfma_f32_16x16x32_bf16(ahi, B.v[0 + n], acc[hh][n], 0, 0, 0);
            acc[hh][n] = __builtin_amdgcn_mfma_f32_16x16x32_bf16(ahi, B.v[4 + n], acc[hh][n], 0, 0, 0);
            acc[hh][n] = __builtin_amdgcn_mfma_f32_16x16x32_bf16(alo, B.v[0 + n], acc[hh][n], 0, 0, 0);
        }
    };

    BSet BA, BB;

    #pragma unroll 1
    for (int rep = 0; rep < REP; ++rep) {
        #pragma unroll
        for (int h = 0; h < 2; ++h)
            #pragma unroll
            for (int n = 0; n < 4; ++n) acc[h][n] = (f32x4){0.f, 0.f, 0.f, 0.f};

        // prologue: B(slab of c0):8, X0:2, X1:2, X2:2
        load_b(0, BA);
        stage_x(0, 0);
        stage_x(1, 1);
        stage_x(2, 2);
        asm volatile("s_waitcnt vmcnt(4)" ::: "memory");
        __builtin_amdgcn_sched_barrier(0);
        __builtin_amdgcn_s_barrier();

        // steady state: identical to v6 — issue 10/2 alternating, wait(12)
        #pragma unroll 1
        for (int c = 0; c < 28; c += 4) {
            load_b(c + 2, BB);
            stage_x(c + 3, (c + 3) & 3);
            asm volatile("s_waitcnt vmcnt(12)" ::: "memory");
            __builtin_amdgcn_sched_barrier(0);
            compute((c + 0) & 3, 0, BA);
            __builtin_amdgcn_s_barrier();

            stage_x(c + 4, (c + 4) & 3);
            asm volatile("s_waitcnt vmcnt(12)" ::: "memory");
            __builtin_amdgcn_sched_barrier(0);
            compute((c + 1) & 3, 1, BA);
            __builtin_amdgcn_s_barrier();

            load_b(c + 4, BA);
            stage_x(c + 5, (c + 5) & 3);
            asm volatile("s_waitcnt vmcnt(12)" ::: "memory");
            __builtin_amdgcn_sched_barrier(0);
            compute((c + 2) & 3, 0, BB);
            __builtin_amdgcn_s_barrier();

            stage_x(c + 6, (c + 6) & 3);
            asm volatile("s_waitcnt vmcnt(12)" ::: "memory");
            __builtin_amdgcn_sched_barrier(0);
            compute((c + 3) & 3, 1, BB);
            __builtin_amdgcn_s_barrier();
        }
        // tail (exact counts, as v6)
        load_b(30, BB);
        stage_x(31, 3);
        asm volatile("s_waitcnt vmcnt(12)" ::: "memory");
        __builtin_amdgcn_sched_barrier(0);
        compute(0, 0, BA);
        __builtin_amdgcn_s_barrier();

        compute(1, 1, BA);
        __builtin_amdgcn_s_barrier();

        asm volatile("s_waitcnt vmcnt(2)" ::: "memory");
        __builtin_amdgcn_sched_barrier(0);
        compute(2, 0, BB);
        __builtin_amdgcn_s_barrier();

        asm volatile("s_waitcnt vmcnt(0)" ::: "memory");
        __builtin_amdgcn_sched_barrier(0);
        compute(3, 1, BB);
        __syncthreads();              // protect xs ring before next rep restages
    }

    // epilogue: 4-way k-quarter reduce into lg (deterministic serial order)
    const int rb = (lane >> 4) << 2;
    const int cb = lane & 15;
    if (q == 0) {
        #pragma unroll
        for (int h = 0; h < 2; ++h)
            #pragma unroll
            for (int n = 0; n < 4; ++n)
                #pragma unroll
                for (int j = 0; j < 4; ++j)
                    lg[h * 16 + rb + j][n * 16 + cb] = acc[h][n][j];
    }
    __syncthreads();
    if (q == 1) {
        #pragma unroll
        for (int h = 0; h < 2; ++h)
            #pragma unroll
            for (int n = 0; n < 4; ++n)
                #pragma unroll
                for (int j = 0; j < 4; ++j)
                    lg[h * 16 + rb + j][n * 16 + cb] += acc[h][n][j];
    }
    __syncthreads();
    if (q == 2) {
        #pragma unroll
        for (int h = 0; h < 2; ++h)
            #pragma unroll
            for (int n = 0; n < 4; ++n)
                #pragma unroll
                for (int j = 0; j < 4; ++j)
                    lg[h * 16 + rb + j][n * 16 + cb] += acc[h][n][j];
    }
    __syncthreads();
    if (q == 3) {
        #pragma unroll
        for (int h = 0; h < 2; ++h)
            #pragma unroll
            for (int n = 0; n < 4; ++n)
                #pragma unroll
                for (int j = 0; j < 4; ++j)
                    lg[h * 16 + rb + j][n * 16 + cb] += acc[h][n][j];
    }
    __syncthreads();

    if (t < BM) {
        float m  = lg[t][0];
        int   mi = 0;
        #pragma unroll
        for (int e = 1; e < NE; ++e) {
            float v = lg[t][e];
            if (v > m) { m = v; mi = e; }
        }
        s_idx[t] = mi;
        out[row0 + t]         = (float)mi;
        out[BATCH + row0 + t] = m;
    }
    __syncthreads();

    float* mask = out + 2 * (size_t)BATCH;
    int r  = t >> 3;
    int c0 = (t & 7) * 8;
    int mi = s_idx[r];
    #pragma unroll
    for (int i = 0; i < 2; ++i) {
        f32x4 v;
        #pragma unroll
        for (int j = 0; j < 4; ++j) v[j] = (c0 + i * 4 + j == mi) ? 1.0f : 0.0f;
        *(f32x4*)&mask[(size_t)(row0 + r) * NE + c0 + i * 4] = v;
    }
}

extern "C" void kernel_launch(void* const* d_in, const int* in_sizes, int n_in,
                              void* d_out, int out_size, void* d_ws, size_t ws_size,
                              hipStream_t stream) {
    const float* x = (const float*)d_in[0];
    const float* w = (const float*)d_in[1];
    float* out     = (float*)d_out;
    unsigned short* wf = (unsigned short*)d_ws;   // 512 KB

    wconv_kernel<<<dim3(512), dim3(256), 0, stream>>>(w, wf);
    gate_kernel<<<dim3(BATCH / BM), dim3(NT), 0, stream>>>(x, wf, out);
}

// Round 14
// 44.349 us; speedup vs baseline: 1.7673x; 1.7673x over previous
//
#include <hip/hip_runtime.h>

// Top1Gate via bf16x3-split MFMA GEMM, v15.
// logits = x @ W^T [16384,64]; idx = argmax; scores = max; mask = one-hot.
// Output flat (float32): [idx 16384][scores 16384][mask 16384*64]
//
// v15 vs v6 — built on the R13 diagnostic (per-CU VMEM path ~21B/cyc is the
// wall; warm==cold sweeps, all pipes <20%): halve B bytes/CU. BM=64 (256
// blocks, 1/CU), NT=512 (8 waves = 2 row-groups x 4 k-quarters, 2/SIMD).
// B staged once per kblk as a 32KB LDS slab (coalesced linear gload_lds from
// fragment-major wf), shared by rt-wave pairs -> B/CU 1MB -> 512KB, VMEM
// instrs -33%. x chunk = 64r x 128k (32KB), both buffers double-buffered,
// one vmcnt(8) wait per chunk. 1-granular XOR swizzle (fixes the measured
// 1.8M bank conflicts). LDS 144.5KB.

typedef float  f32x4  __attribute__((ext_vector_type(4)));
typedef short  bf16x8 __attribute__((ext_vector_type(8)));

constexpr int BATCH = 16384;
constexpr int DM    = 2048;
constexpr int NE    = 64;
constexpr int BM    = 64;          // rows per block
constexpr int NT    = 512;         // 8 waves: rt (2) x q (4)
constexpr int NCH   = 16;          // kblk chunks of 64r x 128k

// wf layout (d_ws, ushort): [ks=64][term=2][tile=4][lane=64][j=8]
// value = w_term[expert = tile*16 + (lane&15)][k = ks*32 + (lane>>4)*8 + j]

__device__ __forceinline__ void split_bf16(float f, unsigned short& hi, unsigned short& lo) {
    unsigned u  = __float_as_uint(f);
    unsigned h  = (u + 0x8000u) >> 16;           // round-half-up to bf16
    float    hf = __uint_as_float(h << 16);
    unsigned l  = __float_as_uint(f - hf) >> 16; // truncate residual
    hi = (unsigned short)h;
    lo = (unsigned short)l;
}

__global__ __launch_bounds__(256, 1)
void wconv_kernel(const float* __restrict__ w, unsigned short* __restrict__ wf) {
    int i  = blockIdx.x * 256 + threadIdx.x;     // 0..131071
    int ks = i >> 11;
    int n  = (i >> 9) & 3;
    int l  = (i >> 3) & 63;
    int j  = i & 7;
    int e  = n * 16 + (l & 15);
    int k  = ks * 32 + (l >> 4) * 8 + j;
    float v = w[(size_t)e * DM + k];
    unsigned short hi, lo;
    split_bf16(v, hi, lo);
    int base = ((ks * 2 + 0) * 4 + n) * 512 + l * 8 + j;
    wf[base]        = hi;               // term 0
    wf[base + 2048] = lo;               // term 1
}

#define WAITV(N) do { asm volatile("s_waitcnt vmcnt(" #N ")" ::: "memory"); \
                      __builtin_amdgcn_sched_barrier(0); } while (0)
#define BARR     do { __builtin_amdgcn_sched_barrier(0); \
                      __builtin_amdgcn_s_barrier(); \
                      __builtin_amdgcn_sched_barrier(0); } while (0)

__global__ __launch_bounds__(NT, 1)
void gate_kernel(const float* __restrict__ x,
                 const unsigned short* __restrict__ wf,
                 float* __restrict__ out) {
    __shared__ alignas(16) float          xs[2][BM * 32 * 4];      // 2 x 32 KB
    __shared__ alignas(16) unsigned short bs[2][4 * 4096];         // 2 x 32 KB slabs
    __shared__ float lg[BM][NE + 1];                               // stride 65
    __shared__ int   s_idx[BM];

    const int t     = threadIdx.x;
    const int lane  = t & 63;
    const int wv    = t >> 6;
    const int rt    = wv >> 2;               // row-group 0/1 (32 rows)
    const int q     = wv & 3;                // k-quarter within kblk
    const int row0  = blockIdx.x * BM;
    const int phase = blockIdx.x & 15;       // kblk de-phase (R5)

    f32x4 acc[2][4];                          // [sub 16-row tile][expert tile]
    #pragma unroll
    for (int s = 0; s < 2; ++s)
        #pragma unroll
        for (int n = 0; n < 4; ++n) acc[s][n] = (f32x4){0.f, 0.f, 0.f, 0.f};

    auto ckOf = [&](int c) { return (c + phase) & 15; };

    // stage x chunk c: 64 rows x 128 k = 2048 f4; 4 instrs/thread; 512B runs;
    // source pre-swizzled 1-granular, LDS dest linear.
    auto stage_x = [&](int c) {
        const float* xg = x + (size_t)row0 * DM + ckOf(c) * 128;
        float* dst = &xs[c & 1][0];
        #pragma unroll
        for (int i = 0; i < 4; ++i) {
            int d  = i * NT + t;            // 0..2047 linear dest f4 slot
            int r  = d >> 5;                // row 0..63
            int sd = d & 31;
            int sr = sd ^ (r & 7);          // pre-swizzled source
            __builtin_amdgcn_global_load_lds(
                (const __attribute__((address_space(1))) void*)(xg + (size_t)r * DM + sr * 4),
                (__attribute__((address_space(3))) void*)(dst + d * 4),
                16, 0, 0);
        }
    };

    // stage B slab for chunk c: 32 KB contiguous from wf (4 ks), linear.
    auto stage_b = [&](int c) {
        const unsigned short* wg = wf + (size_t)ckOf(c) * 4 * 4096;
        unsigned short* dst = &bs[c & 1][0];
        #pragma unroll
        for (int i = 0; i < 4; ++i) {
            int d = i * NT + t;             // 0..2047 (16B units)
            __builtin_amdgcn_global_load_lds(
                (const __attribute__((address_space(1))) void*)(wg + (size_t)d * 8),
                (__attribute__((address_space(3))) void*)(dst + (size_t)d * 8),
                16, 0, 0);
        }
    };

    // compute chunk c: this wave = rows rt*32..+31, k-step q (32k of the 128).
    // B fragments from slab (contiguous-per-lane b128 = conflict-free);
    // x from swizzled slots; split x hi/lo in VALU; 24 MFMA.
    auto compute = [&](int c) {
        const float*          src  = &xs[c & 1][0];
        const unsigned short* slab = &bs[c & 1][0];
        #pragma unroll
        for (int sub = 0; sub < 2; ++sub) {
            const int row = rt * 32 + sub * 16 + (lane & 15);
            const int s0  = q * 8 + ((lane >> 4) << 1);
            f32x4 a0 = *(const f32x4*)(src + (size_t)(row * 32 + ((s0 + 0) ^ (row & 7))) * 4);
            f32x4 a1 = *(const f32x4*)(src + (size_t)(row * 32 + ((s0 + 1) ^ (row & 7))) * 4);
            bf16x8 ahi, alo;
            #pragma unroll
            for (int j = 0; j < 8; ++j) {
                float f = (j < 4) ? a0[j] : a1[j - 4];
                unsigned short h, l;
                split_bf16(f, h, l);
                ahi[j] = (short)h;
                alo[j] = (short)l;
            }
            #pragma unroll
            for (int n = 0; n < 4; ++n) {
                bf16x8 bhi = *(const bf16x8*)(slab + (size_t)q * 4096 + (0 * 4 + n) * 512 + lane * 8);
                bf16x8 blo = *(const bf16x8*)(slab + (size_t)q * 4096 + (1 * 4 + n) * 512 + lane * 8);
                acc[sub][n] = __builtin_amdgcn_mfma_f32_16x16x32_bf16(ahi, bhi, acc[sub][n], 0, 0, 0);
                acc[sub][n] = __builtin_amdgcn_mfma_f32_16x16x32_bf16(ahi, blo, acc[sub][n], 0, 0, 0);
                acc[sub][n] = __builtin_amdgcn_mfma_f32_16x16x32_bf16(alo, bhi, acc[sub][n], 0, 0, 0);
            }
        }
    };

    // prologue: chunk0 + chunk1 in flight (8+8), drain chunk0
    stage_x(0); stage_b(0);
    stage_x(1); stage_b(1);
    WAITV(8);
    BARR;

    // steady: compute(c); barrier frees slot c&1; stage(c+2) into it;
    // wait(8) drains chunk c+1 (leaves c+2 in flight); barrier.
    #pragma unroll 1
    for (int c = 0; c < NCH - 2; ++c) {
        compute(c);
        BARR;
        stage_x(c + 2); stage_b(c + 2);
        WAITV(8);
        BARR;
    }
    // c = 14: nothing left to stage; drain chunk 15
    compute(NCH - 2);
    BARR;
    WAITV(0);
    BARR;
    compute(NCH - 1);
    __syncthreads();

    // 4-way k-quarter reduce into lg (deterministic serial order).
    // C/D layout: row_local = rt*32 + sub*16 + (lane>>4)*4 + j, col = n*16+(lane&15)
    const int rb = (lane >> 4) << 2;
    const int cb = lane & 15;
    if (q == 0) {
        #pragma unroll
        for (int sub = 0; sub < 2; ++sub)
            #pragma unroll
            for (int n = 0; n < 4; ++n)
                #pragma unroll
                for (int j = 0; j < 4; ++j)
                    lg[rt * 32 + sub * 16 + rb + j][n * 16 + cb] = acc[sub][n][j];
    }
    __syncthreads();
    if (q == 1) {
        #pragma unroll
        for (int sub = 0; sub < 2; ++sub)
            #pragma unroll
            for (int n = 0; n < 4; ++n)
                #pragma unroll
                for (int j = 0; j < 4; ++j)
                    lg[rt * 32 + sub * 16 + rb + j][n * 16 + cb] += acc[sub][n][j];
    }
    __syncthreads();
    if (q == 2) {
        #pragma unroll
        for (int sub = 0; sub < 2; ++sub)
            #pragma unroll
            for (int n = 0; n < 4; ++n)
                #pragma unroll
                for (int j = 0; j < 4; ++j)
                    lg[rt * 32 + sub * 16 + rb + j][n * 16 + cb] += acc[sub][n][j];
    }
    __syncthreads();
    if (q == 3) {
        #pragma unroll
        for (int sub = 0; sub < 2; ++sub)
            #pragma unroll
            for (int n = 0; n < 4; ++n)
                #pragma unroll
                for (int j = 0; j < 4; ++j)
                    lg[rt * 32 + sub * 16 + rb + j][n * 16 + cb] += acc[sub][n][j];
    }
    __syncthreads();

    if (t < BM) {
        float m  = lg[t][0];
        int   mi = 0;
        #pragma unroll
        for (int e = 1; e < NE; ++e) {
            float v = lg[t][e];
            if (v > m) { m = v; mi = e; }
        }
        s_idx[t] = mi;
        out[row0 + t]         = (float)mi;
        out[BATCH + row0 + t] = m;
    }
    __syncthreads();

    // one-hot mask: 64 rows x 64 = 4096 floats; 8/thread, coalesced f32x4
    float* mask = out + 2 * (size_t)BATCH;
    int r  = t >> 3;
    int c0 = (t & 7) * 8;
    int mi = s_idx[r];
    #pragma unroll
    for (int i = 0; i < 2; ++i) {
        f32x4 v;
        #pragma unroll
        for (int j = 0; j < 4; ++j) v[j] = (c0 + i * 4 + j == mi) ? 1.0f : 0.0f;
        *(f32x4*)&mask[(size_t)(row0 + r) * NE + c0 + i * 4] = v;
    }
}

extern "C" void kernel_launch(void* const* d_in, const int* in_sizes, int n_in,
                              void* d_out, int out_size, void* d_ws, size_t ws_size,
                              hipStream_t stream) {
    const float* x = (const float*)d_in[0];
    const float* w = (const float*)d_in[1];
    float* out     = (float*)d_out;
    unsigned short* wf = (unsigned short*)d_ws;   // 512 KB

    wconv_kernel<<<dim3(512), dim3(256), 0, stream>>>(w, wf);
    gate_kernel<<<dim3(BATCH / BM), dim3(NT), 0, stream>>>(x, wf, out);
}